// Round 8
// baseline (676.538 us; speedup 1.0000x reference)
//
#include <hip/hip_runtime.h>
#include <stdint.h>

#pragma clang fp contract(off)

#define NN 1024
#define BB 2048
#define ENS 1000
#define KK 32

#define NEGC -1.0e9f
#define PADV -1.0e10f
#define L2E 1.44269504088896341f
#define LN2 0.69314718055994531f

// ===================== XLA:CPU float32 math replicas (exact path) =====================
__device__ __forceinline__ float xla_expf(float xin) {
  float x = fminf(xin, 88.3762626647950f);
  x = fmaxf(x, -88.3762626647949f);
  float fx = floorf(__builtin_fmaf(x, 1.44269504088896341f, 0.5f));
  x = __builtin_fmaf(fx, -0.693359375f, x);
  x = __builtin_fmaf(fx, 2.12194440e-4f, x);
  float z = x * x;
  float y = 1.9875691500e-4f;
  y = __builtin_fmaf(y, x, 1.3981999507e-3f);
  y = __builtin_fmaf(y, x, 8.3334519073e-3f);
  y = __builtin_fmaf(y, x, 4.1665795894e-2f);
  y = __builtin_fmaf(y, x, 1.6666665459e-1f);
  y = __builtin_fmaf(y, x, 5.0000001201e-1f);
  y = __builtin_fmaf(y, z, x);
  y = y + 1.0f;
  int n = (int)fx;
  float two_n = __int_as_float((n + 127) << 23);
  return y * two_n;
}

__device__ __forceinline__ float xla_logf(float uin) {
  int ib = __float_as_int(uin);
  float e = (float)((ib >> 23) - 126);
  float m = __int_as_float((ib & 0x007FFFFF) | 0x3F000000);
  bool lt = m < 0.707106781186547524f;
  float tmp = lt ? m : 0.0f;
  e = lt ? (e - 1.0f) : e;
  float x = m - 1.0f;
  x = x + tmp;
  float z = x * x;
  float y = 7.0376836292e-2f;
  y = __builtin_fmaf(y, x, -1.1514610310e-1f);
  y = __builtin_fmaf(y, x, 1.1676998740e-1f);
  y = __builtin_fmaf(y, x, -1.2420140846e-1f);
  y = __builtin_fmaf(y, x, 1.4249322787e-1f);
  y = __builtin_fmaf(y, x, -1.6668057665e-1f);
  y = __builtin_fmaf(y, x, 2.0000714765e-1f);
  y = __builtin_fmaf(y, x, -2.4999993993e-1f);
  y = __builtin_fmaf(y, x, 3.3333331174e-1f);
  y = y * x;
  y = y * z;
  y = __builtin_fmaf(e, -2.12194440e-4f, y);
  y = __builtin_fmaf(z, -0.5f, y);
  x = x + y;
  x = __builtin_fmaf(e, 0.693359375f, x);
  return x;
}

__device__ __forceinline__ float xla_log1pf(float x) {
  float lg = xla_logf(x + 1.0f);
  float sm = __builtin_fmaf(-0.5f, x, 1.0f) * x;
  return (fabsf(x) < 1e-4f) ? sm : lg;
}

__device__ __forceinline__ float xla_logsigmoid(float v) {
  float y = -v;
  float amax = fmaxf(y, 0.0f);
  float sp = amax + xla_log1pf(xla_expf(-fabsf(y)));
  return -sp + 1e-7f;
}

// ===================== fast math (marginal path only; 2e-2 tolerance) ==============
__device__ __forceinline__ float fexp2(float x) { return __builtin_amdgcn_exp2f(x); }
__device__ __forceinline__ float flog2(float x) { return __builtin_amdgcn_logf(x); }

__device__ __forceinline__ float fast_lae(float a, float b) {
  float m = fmaxf(a, b);
  float d = -fabsf(a - b);
  float e = fexp2(d * L2E);
  return m + flog2(1.0f + e) * LN2;
}

// fast logsigmoid (marg only)
__device__ __forceinline__ float alo_fast(float v) {
  float y = -v;
  float e = fexp2(-fabsf(y) * L2E);
  float sp = fmaxf(y, 0.0f) + flog2(1.0f + e) * LN2;
  return -sp + 1e-7f;
}

// ===================== DPP cross-lane helpers =====================
template <int CTRL, int ROWM>
__device__ __forceinline__ float dppz(float x) {
  return __int_as_float(__builtin_amdgcn_update_dpp(0, __float_as_int(x), CTRL, ROWM, 0xF, false));
}

__device__ __forceinline__ float shup1(float x) { return dppz<0x138, 0xF>(x); }  // wave_shr:1

// per-half (32-lane) sum; total lands at g==31 of each half
__device__ __forceinline__ float sum_half_last(float x) {
  x += dppz<0x111, 0xF>(x);   // row_shr:1
  x += dppz<0x112, 0xF>(x);   // row_shr:2
  x += dppz<0x114, 0xF>(x);   // row_shr:4
  x += dppz<0x118, 0xF>(x);   // row_shr:8
  x += dppz<0x142, 0xA>(x);   // row_bcast15 into rows 1&3
  return x;
}

// ===================== JAX threefry2x32, key(42) =====================
__device__ __forceinline__ uint32_t rotl_(uint32_t v, int s) { return (v << s) | (v >> (32 - s)); }

__device__ __forceinline__ uint32_t threefry_fold(uint32_t x0, uint32_t x1) {
  const uint32_t ks0 = 0u;
  const uint32_t ks1 = 42u;
  const uint32_t ks2 = 0x1BD11BDAu ^ 42u;
  uint32_t v0 = x0 + ks0;
  uint32_t v1 = x1 + ks1;
#define TF_R(rr) { v0 += v1; v1 = rotl_(v1, rr); v1 ^= v0; }
  TF_R(13) TF_R(15) TF_R(26) TF_R(6)
  v0 += ks1; v1 += ks2 + 1u;
  TF_R(17) TF_R(29) TF_R(16) TF_R(24)
  v0 += ks2; v1 += ks0 + 2u;
  TF_R(13) TF_R(15) TF_R(26) TF_R(6)
  v0 += ks0; v1 += ks1 + 3u;
  TF_R(17) TF_R(29) TF_R(16) TF_R(24)
  v0 += ks1; v1 += ks2 + 4u;
  TF_R(13) TF_R(15) TF_R(26) TF_R(6)
  v0 += ks2; v1 += ks0 + 5u;
#undef TF_R
  return v0 ^ v1;
}

__device__ __forceinline__ float jax_uniform01(uint32_t m) {
  uint32_t bits = threefry_fold(0u, m);
  return __uint_as_float((bits >> 9) | 0x3F800000u) - 1.0f;
}

// ===================== kernel 1: the ONE exact chain + masks + ckpt/fckpt/logZ =====
// block = 2 waves x 2 rows. Up-front: stage a (exact logsigmoid) and u (threefry)
// for the whole row pair into LDS (one barrier). Then wave A = exact backward
// S-scan emitting ckpt + per-item 32-bit sample masks (ballot of u < pv);
// wave B = fast forward F-scan emitting fckpt + logZ. Hazard-free LDS reads.
__global__ __launch_bounds__(128) void k_scan1(const float* __restrict__ scores,
                                               float* __restrict__ ckpt,
                                               float* __restrict__ fckpt,
                                               float* __restrict__ logZ,
                                               uint32_t* __restrict__ masks) {
  __shared__ float la[2][NN];   // 8 KiB
  __shared__ float lu[2][NN];   // 8 KiB
  int w = threadIdx.x >> 6;
  int lane = threadIdx.x & 63;
  int g = lane & 31, half = lane >> 5;
  int row0 = blockIdx.x * 2;

  if (w == 0) {
    #pragma unroll 4
    for (int q = 0; q < 32; ++q) {
      int n = q * 64 + lane;
      int hf = n >> 10, i = n & (NN - 1);
      float x = (i < ENS) ? scores[(size_t)(row0 + hf) * ENS + i] : PADV;
      la[hf][i] = xla_logsigmoid(x);
    }
  } else {
    #pragma unroll 4
    for (int q = 0; q < 32; ++q) {
      int n = q * 64 + lane;
      int hf = n >> 10, i = n & (NN - 1);
      lu[hf][i] = jax_uniform01((uint32_t)(i * BB + row0 + hf));
    }
  }
  __syncthreads();

  int role = w ^ (blockIdx.x & 1);
  int row = row0 + half;
  if (role == 0) {
    // ---- exact backward S-scan + mask generation ----
    float s = NEGC;
    #pragma unroll 1
    for (int seg = 15; seg >= 0; --seg) {
      if (seg <= 14) ckpt[((size_t)seg * BB + row) * 32 + g] = s;
      #pragma unroll 16
      for (int t = 63; t >= 0; --t) {
        int i = seg * 64 + t;
        float a = la[half][i];
        float u = lu[half][i];
        float prev = shup1(s);
        float sh = (g == 0) ? 0.0f : prev;      // S[i+1][g]
        float tv = a + sh;
        float amax = fmaxf(s, tv);
        float snew = amax + xla_log1pf(xla_expf(-fabsf(s - tv)));  // S[i][g+1]
        float pv = xla_expf(tv - snew);         // exp((a+s1)-s2), channel g+1
        pv = fminf(fmaxf(pv, 0.0f), 1.0f);
        s = snew;
        unsigned long long bal = __ballot(u < pv);
        if (lane == 0)  masks[(size_t)i * BB + row0]     = (uint32_t)bal;
        if (lane == 32) masks[(size_t)i * BB + row0 + 1] = (uint32_t)(bal >> 32);
      }
    }
  } else {
    // ---- fast forward F-scan ----
    float F = NEGC;
    #pragma unroll 1
    for (int seg = 0; seg <= 15; ++seg) {
      #pragma unroll 16
      for (int t = 0; t < 64; ++t) {
        float a = la[half][seg * 64 + t];
        float prev = shup1(F);
        float Fj = (g == 0) ? 0.0f : prev;
        F = fast_lae(F, a + Fj);
      }
      if (seg <= 14) fckpt[((size_t)seg * BB + row) * 32 + g] = F;
    }
    if (g == 31) logZ[row] = F;   // F[N][32]
  }
}

// ===================== kernel 2: trivial serial sampler (1 lane = 1 row) ===========
__global__ __launch_bounds__(64) void k_samp(const uint32_t* __restrict__ masks,
                                             uint32_t* __restrict__ bits) {
  int row = blockIdx.x * 64 + threadIdx.x;
  int r = KK;
  uint32_t word = 0;
  #pragma unroll 16
  for (int i = 0; i < NN; ++i) {
    uint32_t mw = masks[(size_t)i * BB + row];
    int inc = (r > 0) ? (int)((mw >> (r - 1)) & 1u) : 0;   // rc==r when r>=1
    r -= inc;
    word |= ((uint32_t)inc) << (i & 31);
    if ((i & 31) == 31) { bits[row * 32 + (i >> 5)] = word; word = 0; }
  }
}

// ===================== kernel 3: marginals, fully parallel (row-pair x segment) ====
__global__ __launch_bounds__(64) void k_marg(const float* __restrict__ scores,
                                             const float* __restrict__ ckpt,
                                             const float* __restrict__ fckpt,
                                             const float* __restrict__ logZ,
                                             float* __restrict__ margOut) {
  __shared__ float Ss[2][65][32];   // 16640 B: [half][t][g] = S channel g+1
  __shared__ float la[2][64];
  int lane = threadIdx.x;
  int g = lane & 31, half = lane >> 5;
  int rp = blockIdx.x >> 4, seg = blockIdx.x & 15;
  int row = rp * 2 + half, base = seg * 64;
  const float* srow = scores + (size_t)row * ENS;

  {
    int i0 = base + g, i1 = base + 32 + g;
    la[half][g]      = alo_fast((i0 < ENS) ? srow[i0] : PADV);
    la[half][32 + g] = alo_fast((i1 < ENS) ? srow[i1] : PADV);
  }
  float s = (seg == 15) ? NEGC : ckpt[((size_t)seg * BB + row) * 32 + g];
  Ss[half][64][g] = s;
  #pragma unroll 8
  for (int t = 63; t >= 0; --t) {
    float a = la[half][t];
    float prev = shup1(s);
    float sh = (g == 0) ? 0.0f : prev;
    s = fast_lae(s, a + sh);
    Ss[half][t][g] = s;
  }
  // single wave: DS ops in-order, no barrier needed
  float F = (seg == 0) ? NEGC : fckpt[((size_t)(seg - 1) * BB + row) * 32 + g];
  float lz = logZ[row];
  #pragma unroll 4
  for (int t = 0; t < 64; ++t) {
    int i = base + t;
    float a = la[half][t];
    float prev = shup1(F);
    float Fj = (g == 0) ? 0.0f : prev;
    float sv = (g == 31) ? 0.0f : Ss[half][t + 1][30 - g];   // S[i+1][31-g]
    float term = fexp2((Fj + sv - lz) * L2E);                // <= ~1, no max pass
    float tot = sum_half_last(term);
    if (g == 31 && i < ENS)
      margOut[(size_t)row * ENS + i] = fexp2(a * L2E) * tot;
    F = fast_lae(F, a + Fj);
  }
}

// ===================== kernel 4: straight-through combine ==========================
__global__ __launch_bounds__(256) void k_final(const float* __restrict__ margOut,
                                               const uint32_t* __restrict__ bits,
                                               float* __restrict__ out) {
  int idx = blockIdx.x * 256 + threadIdx.x;
  if (idx >= BB * ENS) return;
  int row = idx / ENS;
  int i = idx - row * ENS;
  float marg = margOut[idx];
  uint32_t wbits = bits[row * 32 + (i >> 5)];
  float bit = (float)((wbits >> (i & 31)) & 1u);
  out[idx] = (bit - marg) + marg;
}

extern "C" void kernel_launch(void* const* d_in, const int* in_sizes, int n_in,
                              void* d_out, int out_size, void* d_ws, size_t ws_size,
                              hipStream_t stream) {
  const float* scores = (const float*)d_in[0];
  float* outbuf = (float*)d_out;
  float* margOut = outbuf + (size_t)BB * ENS;   // marginals = out upper half

  float* ws = (float*)d_ws;
  float* ckpt = ws;                                   // 15*BB*32 floats
  float* fckpt = ckpt + (size_t)15 * BB * 32;         // 15*BB*32 floats
  float* logZ = fckpt + (size_t)15 * BB * 32;         // BB floats
  uint32_t* masks = (uint32_t*)(logZ + BB);           // BB*NN dwords (8 MB)
  uint32_t* bits = masks + (size_t)BB * NN;           // BB*32 dwords
  (void)in_sizes; (void)n_in; (void)out_size; (void)ws_size;

  hipLaunchKernelGGL(k_scan1, dim3(BB / 2), dim3(128), 0, stream,
                     scores, ckpt, fckpt, logZ, masks);
  hipLaunchKernelGGL(k_samp, dim3(BB / 64), dim3(64), 0, stream, masks, bits);
  hipLaunchKernelGGL(k_marg, dim3((BB / 2) * 16), dim3(64), 0, stream,
                     scores, ckpt, fckpt, logZ, margOut);
  hipLaunchKernelGGL(k_final, dim3((BB * ENS + 255) / 256), dim3(256), 0, stream,
                     margOut, bits, outbuf);
}

// Round 10
// 432.406 us; speedup vs baseline: 1.5646x; 1.5646x over previous
//
#include <hip/hip_runtime.h>
#include <stdint.h>

#pragma clang fp contract(off)

#define NN 1024
#define BB 2048
#define ENS 1000
#define KK 32

#define NEGC -1.0e9f
#define PADV -1.0e10f
#define L2E 1.44269504088896341f
#define LN2 0.69314718055994531f

// ===================== XLA:CPU float32 math replicas (exact path) =====================
__device__ __forceinline__ float xla_expf(float xin) {
  float x = fminf(xin, 88.3762626647950f);
  x = fmaxf(x, -88.3762626647949f);
  float fx = floorf(__builtin_fmaf(x, 1.44269504088896341f, 0.5f));
  x = __builtin_fmaf(fx, -0.693359375f, x);
  x = __builtin_fmaf(fx, 2.12194440e-4f, x);
  float z = x * x;
  float y = 1.9875691500e-4f;
  y = __builtin_fmaf(y, x, 1.3981999507e-3f);
  y = __builtin_fmaf(y, x, 8.3334519073e-3f);
  y = __builtin_fmaf(y, x, 4.1665795894e-2f);
  y = __builtin_fmaf(y, x, 1.6666665459e-1f);
  y = __builtin_fmaf(y, x, 5.0000001201e-1f);
  y = __builtin_fmaf(y, z, x);
  y = y + 1.0f;
  int n = (int)fx;
  float two_n = __int_as_float((n + 127) << 23);
  return y * two_n;
}

__device__ __forceinline__ float xla_logf(float uin) {
  int ib = __float_as_int(uin);
  float e = (float)((ib >> 23) - 126);
  float m = __int_as_float((ib & 0x007FFFFF) | 0x3F000000);
  bool lt = m < 0.707106781186547524f;
  float tmp = lt ? m : 0.0f;
  e = lt ? (e - 1.0f) : e;
  float x = m - 1.0f;
  x = x + tmp;
  float z = x * x;
  float y = 7.0376836292e-2f;
  y = __builtin_fmaf(y, x, -1.1514610310e-1f);
  y = __builtin_fmaf(y, x, 1.1676998740e-1f);
  y = __builtin_fmaf(y, x, -1.2420140846e-1f);
  y = __builtin_fmaf(y, x, 1.4249322787e-1f);
  y = __builtin_fmaf(y, x, -1.6668057665e-1f);
  y = __builtin_fmaf(y, x, 2.0000714765e-1f);
  y = __builtin_fmaf(y, x, -2.4999993993e-1f);
  y = __builtin_fmaf(y, x, 3.3333331174e-1f);
  y = y * x;
  y = y * z;
  y = __builtin_fmaf(e, -2.12194440e-4f, y);
  y = __builtin_fmaf(z, -0.5f, y);
  x = x + y;
  x = __builtin_fmaf(e, 0.693359375f, x);
  return x;
}

__device__ __forceinline__ float xla_log1pf(float x) {
  float lg = xla_logf(x + 1.0f);
  float sm = __builtin_fmaf(-0.5f, x, 1.0f) * x;
  return (fabsf(x) < 1e-4f) ? sm : lg;
}

__device__ __forceinline__ float xla_logsigmoid(float v) {
  float y = -v;
  float amax = fmaxf(y, 0.0f);
  float sp = amax + xla_log1pf(xla_expf(-fabsf(y)));
  return -sp + 1e-7f;
}

// ===================== fast math (marginal path only; 2e-2 tolerance) ==============
__device__ __forceinline__ float fexp2(float x) { return __builtin_amdgcn_exp2f(x); }
__device__ __forceinline__ float flog2(float x) { return __builtin_amdgcn_logf(x); }

__device__ __forceinline__ float fast_lae(float a, float b) {
  float m = fmaxf(a, b);
  float d = -fabsf(a - b);
  float e = fexp2(d * L2E);
  return m + flog2(1.0f + e) * LN2;
}

__device__ __forceinline__ float alo_fast(float v) {
  float y = -v;
  float e = fexp2(-fabsf(y) * L2E);
  float sp = fmaxf(y, 0.0f) + flog2(1.0f + e) * LN2;
  return -sp + 1e-7f;
}

// ===================== DPP / lane helpers =====================
template <int CTRL, int ROWM>
__device__ __forceinline__ float dppz(float x) {
  return __int_as_float(__builtin_amdgcn_update_dpp(0, __float_as_int(x), CTRL, ROWM, 0xF, false));
}

__device__ __forceinline__ float shup1(float x) { return dppz<0x138, 0xF>(x); }  // wave_shr:1

// per-half (32-lane) sum; total lands at g==31 of each half
__device__ __forceinline__ float sum_half_last(float x) {
  x += dppz<0x111, 0xF>(x);   // row_shr:1
  x += dppz<0x112, 0xF>(x);   // row_shr:2
  x += dppz<0x114, 0xF>(x);   // row_shr:4
  x += dppz<0x118, 0xF>(x);   // row_shr:8
  x += dppz<0x142, 0xA>(x);   // row_bcast15 into rows 1&3
  return x;
}

// ===================== JAX threefry2x32, key(42) =====================
__device__ __forceinline__ uint32_t rotl_(uint32_t v, int s) { return (v << s) | (v >> (32 - s)); }

__device__ __forceinline__ uint32_t threefry_fold(uint32_t x0, uint32_t x1) {
  const uint32_t ks0 = 0u;
  const uint32_t ks1 = 42u;
  const uint32_t ks2 = 0x1BD11BDAu ^ 42u;
  uint32_t v0 = x0 + ks0;
  uint32_t v1 = x1 + ks1;
#define TF_R(rr) { v0 += v1; v1 = rotl_(v1, rr); v1 ^= v0; }
  TF_R(13) TF_R(15) TF_R(26) TF_R(6)
  v0 += ks1; v1 += ks2 + 1u;
  TF_R(17) TF_R(29) TF_R(16) TF_R(24)
  v0 += ks2; v1 += ks0 + 2u;
  TF_R(13) TF_R(15) TF_R(26) TF_R(6)
  v0 += ks0; v1 += ks1 + 3u;
  TF_R(17) TF_R(29) TF_R(16) TF_R(24)
  v0 += ks1; v1 += ks2 + 4u;
  TF_R(13) TF_R(15) TF_R(26) TF_R(6)
  v0 += ks2; v1 += ks0 + 5u;
#undef TF_R
  return v0 ^ v1;
}

__device__ __forceinline__ float jax_uniform01(uint32_t m) {
  uint32_t bits = threefry_fold(0u, m);
  return __uint_as_float((bits >> 9) | 0x3F800000u) - 1.0f;
}

// ===================== kernel 1: exact S-chain + channel-words + ckpt/fckpt/logZ ===
// cmask layout: cmask[row*NN + gq*32 + g], bit t = (u < p_{channel g+1}) at item
// gq*32+t. Each lane accumulates its OWN channel word (no cross-lane, no branches);
// one coalesced store per 32-item group.
__global__ __launch_bounds__(128) void k_scan1(const float* __restrict__ scores,
                                               float* __restrict__ ckpt,
                                               float* __restrict__ fckpt,
                                               float* __restrict__ logZ,
                                               uint32_t* __restrict__ cmask) {
  __shared__ float la[2][NN];   // 8 KiB
  __shared__ float lu[2][NN];   // 8 KiB
  int w = threadIdx.x >> 6;
  int lane = threadIdx.x & 63;
  int g = lane & 31, half = lane >> 5;
  int row0 = blockIdx.x * 2;

  if (w == 0) {
    #pragma unroll 4
    for (int q = 0; q < 32; ++q) {
      int n = q * 64 + lane;
      int hf = n >> 10, i = n & (NN - 1);
      float x = (i < ENS) ? scores[(size_t)(row0 + hf) * ENS + i] : PADV;
      la[hf][i] = xla_logsigmoid(x);
    }
  } else {
    #pragma unroll 4
    for (int q = 0; q < 32; ++q) {
      int n = q * 64 + lane;
      int hf = n >> 10, i = n & (NN - 1);
      lu[hf][i] = jax_uniform01((uint32_t)(i * BB + row0 + hf));
    }
  }
  __syncthreads();

  int role = w ^ (blockIdx.x & 1);
  int row = row0 + half;
  if (role == 0) {
    // ---- exact backward S-scan; per-lane channel-word accumulation ----
    float s = NEGC;
    #pragma unroll 1
    for (int seg = 15; seg >= 0; --seg) {
      if (seg <= 14) ckpt[((size_t)seg * BB + row) * 32 + g] = s;
      uint32_t cw1 = 0u, cw0 = 0u;
      #pragma unroll
      for (int t = 63; t >= 32; --t) {
        int i = seg * 64 + t;
        float a = la[half][i];
        float u = lu[half][i];
        float prev = shup1(s);
        float sh = (g == 0) ? 0.0f : prev;      // S[i+1][g]
        float tv = a + sh;                      // a + s1
        float amax = fmaxf(s, tv);
        float snew = amax + xla_log1pf(xla_expf(-fabsf(s - tv)));  // S[i][g+1]
        float pv = xla_expf(tv - snew);         // p for channel g+1
        s = snew;
        // clip(p,0,1) is a no-op for (u < clip(p)) given u in [0,1): drop it.
        cw1 |= (u < pv) ? (1u << (t - 32)) : 0u;
      }
      #pragma unroll
      for (int t = 31; t >= 0; --t) {
        int i = seg * 64 + t;
        float a = la[half][i];
        float u = lu[half][i];
        float prev = shup1(s);
        float sh = (g == 0) ? 0.0f : prev;
        float tv = a + sh;
        float amax = fmaxf(s, tv);
        float snew = amax + xla_log1pf(xla_expf(-fabsf(s - tv)));
        float pv = xla_expf(tv - snew);
        s = snew;
        cw0 |= (u < pv) ? (1u << t) : 0u;
      }
      uint32_t* cm = cmask + (size_t)row * NN + seg * 64;
      cm[32 + g] = cw1;   // group seg*2+1
      cm[g] = cw0;        // group seg*2
    }
  } else {
    // ---- fast forward F-scan ----
    float F = NEGC;
    #pragma unroll 1
    for (int seg = 0; seg <= 15; ++seg) {
      #pragma unroll 16
      for (int t = 0; t < 64; ++t) {
        float a = la[half][seg * 64 + t];
        float prev = shup1(F);
        float Fj = (g == 0) ? 0.0f : prev;
        F = fast_lae(F, a + Fj);
      }
      if (seg <= 14) fckpt[((size_t)seg * BB + row) * 32 + g] = F;
    }
    if (g == 31) logZ[row] = F;   // F[N][32]
  }
}

// ===================== kernel 2: serial sampler — wave per row, readlane chain =====
// Lane l holds the channel word for (group base+0, channel l) [l<32] or
// (group base+1, channel l-32) [l>=32]. Decision chain is SALU + v_readlane.
__global__ __launch_bounds__(64) void k_samp(const uint32_t* __restrict__ cmask,
                                             uint32_t* __restrict__ bits) {
  int row = blockIdx.x;
  int lane = threadIdx.x;
  const uint32_t* base = cmask + (size_t)row * NN;
  int r = KK;
  #pragma unroll 1
  for (int q = 0; q < 16; ++q) {
    uint32_t mw = base[q * 64 + lane];   // one coalesced 256B load per 64 items
    uint32_t w0 = 0u, w1 = 0u;
    #pragma unroll
    for (int t = 0; t < 32; ++t) {
      int rl = (r > 0) ? (r - 1) : 0;
      uint32_t wv = (uint32_t)__builtin_amdgcn_readlane((int)mw, rl);
      int inc = (int)((wv >> t) & 1u) & (int)(r > 0);
      r -= inc;
      w0 |= ((uint32_t)inc) << t;
    }
    #pragma unroll
    for (int t = 0; t < 32; ++t) {
      int rl = (r > 0) ? (r - 1) : 0;
      uint32_t wv = (uint32_t)__builtin_amdgcn_readlane((int)mw, 32 + rl);
      int inc = (int)((wv >> t) & 1u) & (int)(r > 0);
      r -= inc;
      w1 |= ((uint32_t)inc) << t;
    }
    if (lane == 0) {
      bits[row * 32 + q * 2] = w0;
      bits[row * 32 + q * 2 + 1] = w1;
    }
  }
}

// ===================== kernel 3: marginals (verbatim round-8 passing version) ======
__global__ __launch_bounds__(64) void k_marg(const float* __restrict__ scores,
                                             const float* __restrict__ ckpt,
                                             const float* __restrict__ fckpt,
                                             const float* __restrict__ logZ,
                                             float* __restrict__ margOut) {
  __shared__ float Ss[2][65][32];   // [half][t][g] = S channel g+1
  __shared__ float la[2][64];
  int lane = threadIdx.x;
  int g = lane & 31, half = lane >> 5;
  int rp = blockIdx.x >> 4, seg = blockIdx.x & 15;
  int row = rp * 2 + half, base = seg * 64;
  const float* srow = scores + (size_t)row * ENS;

  {
    int i0 = base + g, i1 = base + 32 + g;
    la[half][g]      = alo_fast((i0 < ENS) ? srow[i0] : PADV);
    la[half][32 + g] = alo_fast((i1 < ENS) ? srow[i1] : PADV);
  }
  float s = (seg == 15) ? NEGC : ckpt[((size_t)seg * BB + row) * 32 + g];
  Ss[half][64][g] = s;
  #pragma unroll 8
  for (int t = 63; t >= 0; --t) {
    float a = la[half][t];
    float prev = shup1(s);
    float sh = (g == 0) ? 0.0f : prev;
    s = fast_lae(s, a + sh);
    Ss[half][t][g] = s;
  }
  // single wave: DS ops in-order, no barrier needed
  float F = (seg == 0) ? NEGC : fckpt[((size_t)(seg - 1) * BB + row) * 32 + g];
  float lz = logZ[row];
  #pragma unroll 4
  for (int t = 0; t < 64; ++t) {
    int i = base + t;
    float a = la[half][t];
    float prev = shup1(F);
    float Fj = (g == 0) ? 0.0f : prev;
    float sv = (g == 31) ? 0.0f : Ss[half][t + 1][30 - g];   // S[i+1][31-g]
    float term = fexp2((Fj + sv - lz) * L2E);                // <= ~1, no max pass
    float tot = sum_half_last(term);
    if (g == 31 && i < ENS)
      margOut[(size_t)row * ENS + i] = fexp2(a * L2E) * tot;
    F = fast_lae(F, a + Fj);
  }
}

// ===================== kernel 4: straight-through combine ==========================
__global__ __launch_bounds__(256) void k_final(const float* __restrict__ margOut,
                                               const uint32_t* __restrict__ bits,
                                               float* __restrict__ out) {
  int idx = blockIdx.x * 256 + threadIdx.x;
  if (idx >= BB * ENS) return;
  int row = idx / ENS;
  int i = idx - row * ENS;
  float marg = margOut[idx];
  uint32_t wbits = bits[row * 32 + (i >> 5)];
  float bit = (float)((wbits >> (i & 31)) & 1u);
  out[idx] = (bit - marg) + marg;
}

extern "C" void kernel_launch(void* const* d_in, const int* in_sizes, int n_in,
                              void* d_out, int out_size, void* d_ws, size_t ws_size,
                              hipStream_t stream) {
  const float* scores = (const float*)d_in[0];
  float* outbuf = (float*)d_out;
  float* margOut = outbuf + (size_t)BB * ENS;   // marginals = out upper half

  float* ws = (float*)d_ws;
  float* ckpt = ws;                                   // 15*BB*32 floats
  float* fckpt = ckpt + (size_t)15 * BB * 32;         // 15*BB*32 floats
  float* logZ = fckpt + (size_t)15 * BB * 32;         // BB floats
  uint32_t* cmask = (uint32_t*)(logZ + BB);           // BB*NN dwords (8 MB)
  uint32_t* bits = cmask + (size_t)BB * NN;           // BB*32 dwords
  (void)in_sizes; (void)n_in; (void)out_size; (void)ws_size;

  hipLaunchKernelGGL(k_scan1, dim3(BB / 2), dim3(128), 0, stream,
                     scores, ckpt, fckpt, logZ, cmask);
  hipLaunchKernelGGL(k_samp, dim3(BB), dim3(64), 0, stream, cmask, bits);
  hipLaunchKernelGGL(k_marg, dim3((BB / 2) * 16), dim3(64), 0, stream,
                     scores, ckpt, fckpt, logZ, margOut);
  hipLaunchKernelGGL(k_final, dim3((BB * ENS + 255) / 256), dim3(256), 0, stream,
                     margOut, bits, outbuf);
}

// Round 11
// 398.655 us; speedup vs baseline: 1.6971x; 1.0847x over previous
//
#include <hip/hip_runtime.h>
#include <stdint.h>

#pragma clang fp contract(off)

#define NN 1024
#define BB 2048
#define ENS 1000
#define KK 32

#define NEGC -1.0e9f
#define PADV -1.0e10f
#define L2E 1.44269504088896341f
#define LN2 0.69314718055994531f

// ===================== XLA:CPU float32 math replicas (exact path) =====================
__device__ __forceinline__ float xla_expf(float xin) {
  float x = fminf(xin, 88.3762626647950f);
  x = fmaxf(x, -88.3762626647949f);
  float fx = floorf(__builtin_fmaf(x, 1.44269504088896341f, 0.5f));
  x = __builtin_fmaf(fx, -0.693359375f, x);
  x = __builtin_fmaf(fx, 2.12194440e-4f, x);
  float z = x * x;
  float y = 1.9875691500e-4f;
  y = __builtin_fmaf(y, x, 1.3981999507e-3f);
  y = __builtin_fmaf(y, x, 8.3334519073e-3f);
  y = __builtin_fmaf(y, x, 4.1665795894e-2f);
  y = __builtin_fmaf(y, x, 1.6666665459e-1f);
  y = __builtin_fmaf(y, x, 5.0000001201e-1f);
  y = __builtin_fmaf(y, z, x);
  y = y + 1.0f;
  int n = (int)fx;
  float two_n = __int_as_float((n + 127) << 23);
  return y * two_n;
}

__device__ __forceinline__ float xla_logf(float uin) {
  int ib = __float_as_int(uin);
  float e = (float)((ib >> 23) - 126);
  float m = __int_as_float((ib & 0x007FFFFF) | 0x3F000000);
  bool lt = m < 0.707106781186547524f;
  float tmp = lt ? m : 0.0f;
  e = lt ? (e - 1.0f) : e;
  float x = m - 1.0f;
  x = x + tmp;
  float z = x * x;
  float y = 7.0376836292e-2f;
  y = __builtin_fmaf(y, x, -1.1514610310e-1f);
  y = __builtin_fmaf(y, x, 1.1676998740e-1f);
  y = __builtin_fmaf(y, x, -1.2420140846e-1f);
  y = __builtin_fmaf(y, x, 1.4249322787e-1f);
  y = __builtin_fmaf(y, x, -1.6668057665e-1f);
  y = __builtin_fmaf(y, x, 2.0000714765e-1f);
  y = __builtin_fmaf(y, x, -2.4999993993e-1f);
  y = __builtin_fmaf(y, x, 3.3333331174e-1f);
  y = y * x;
  y = y * z;
  y = __builtin_fmaf(e, -2.12194440e-4f, y);
  y = __builtin_fmaf(z, -0.5f, y);
  x = x + y;
  x = __builtin_fmaf(e, 0.693359375f, x);
  return x;
}

__device__ __forceinline__ float xla_log1pf(float x) {
  float lg = xla_logf(x + 1.0f);
  float sm = __builtin_fmaf(-0.5f, x, 1.0f) * x;
  return (fabsf(x) < 1e-4f) ? sm : lg;
}

__device__ __forceinline__ float xla_logsigmoid(float v) {
  float y = -v;
  float amax = fmaxf(y, 0.0f);
  float sp = amax + xla_log1pf(xla_expf(-fabsf(y)));
  return -sp + 1e-7f;
}

// ===================== fast math (marginal path only; 2e-2 tolerance) ==============
__device__ __forceinline__ float fexp2(float x) { return __builtin_amdgcn_exp2f(x); }
__device__ __forceinline__ float flog2(float x) { return __builtin_amdgcn_logf(x); }

__device__ __forceinline__ float fast_lae(float a, float b) {
  float m = fmaxf(a, b);
  float d = -fabsf(a - b);
  float e = fexp2(d * L2E);
  return m + flog2(1.0f + e) * LN2;
}

__device__ __forceinline__ float alo_fast(float v) {
  float y = -v;
  float e = fexp2(-fabsf(y) * L2E);
  float sp = fmaxf(y, 0.0f) + flog2(1.0f + e) * LN2;
  return -sp + 1e-7f;
}

// ===================== DPP / lane helpers =====================
template <int CTRL, int ROWM>
__device__ __forceinline__ float dppz(float x) {
  return __int_as_float(__builtin_amdgcn_update_dpp(0, __float_as_int(x), CTRL, ROWM, 0xF, false));
}

__device__ __forceinline__ float shup1(float x) { return dppz<0x138, 0xF>(x); }  // wave_shr:1

// per-half (32-lane) sum; total lands at g==31 of each half
__device__ __forceinline__ float sum_half_last(float x) {
  x += dppz<0x111, 0xF>(x);   // row_shr:1
  x += dppz<0x112, 0xF>(x);   // row_shr:2
  x += dppz<0x114, 0xF>(x);   // row_shr:4
  x += dppz<0x118, 0xF>(x);   // row_shr:8
  x += dppz<0x142, 0xA>(x);   // row_bcast15 into rows 1&3
  return x;
}

// ===================== JAX threefry2x32, key(42) =====================
__device__ __forceinline__ uint32_t rotl_(uint32_t v, int s) { return (v << s) | (v >> (32 - s)); }

__device__ __forceinline__ uint32_t threefry_fold(uint32_t x0, uint32_t x1) {
  const uint32_t ks0 = 0u;
  const uint32_t ks1 = 42u;
  const uint32_t ks2 = 0x1BD11BDAu ^ 42u;
  uint32_t v0 = x0 + ks0;
  uint32_t v1 = x1 + ks1;
#define TF_R(rr) { v0 += v1; v1 = rotl_(v1, rr); v1 ^= v0; }
  TF_R(13) TF_R(15) TF_R(26) TF_R(6)
  v0 += ks1; v1 += ks2 + 1u;
  TF_R(17) TF_R(29) TF_R(16) TF_R(24)
  v0 += ks2; v1 += ks0 + 2u;
  TF_R(13) TF_R(15) TF_R(26) TF_R(6)
  v0 += ks0; v1 += ks1 + 3u;
  TF_R(17) TF_R(29) TF_R(16) TF_R(24)
  v0 += ks1; v1 += ks2 + 4u;
  TF_R(13) TF_R(15) TF_R(26) TF_R(6)
  v0 += ks2; v1 += ks0 + 5u;
#undef TF_R
  return v0 ^ v1;
}

__device__ __forceinline__ float jax_uniform01(uint32_t m) {
  uint32_t bits = threefry_fold(0u, m);
  return __uint_as_float((bits >> 9) | 0x3F800000u) - 1.0f;
}

// ===================== kernel 1: 3-role pipeline {S, PV, F} ========================
// 2 rows per block, 3 waves, roles rotated by blockIdx%3.
//  S : exact backward chain; emits d = tv - snew into 2-slot LDS ring;
//      ckpt every 32 items (ckpt[gq] = S[(gq+1)*32], gq<=30).
//  PV: consumes ring one phase behind; threefry-u; p = xla_expf(d); packs bits
//      into per-channel words; stores cmask[row][gq*32+g].
//  F : fast forward scan; fckpt[gq] = F[(gq+1)*32] (gq<=30); logZ.
__global__ __launch_bounds__(192) void k_scan1(const float* __restrict__ scores,
                                               float* __restrict__ ckpt,
                                               float* __restrict__ fckpt,
                                               float* __restrict__ logZ,
                                               uint32_t* __restrict__ cmask) {
  __shared__ float la[2][NN];            // 8 KiB   exact logsigmoid(a)
  __shared__ float ring[2][2][32][32];   // 16 KiB  [slot][half][t][ch]
  __shared__ float lu[2][32];            // 256 B   PV-private u staging
  int w = threadIdx.x >> 6;
  int lane = threadIdx.x & 63;
  int g = lane & 31, half = lane >> 5;
  int row0 = blockIdx.x * 2;
  int row = row0 + half;

  for (int n = threadIdx.x; n < 2 * NN; n += 192) {
    int hf = n >> 10, i = n & (NN - 1);
    float x = (i < ENS) ? scores[(size_t)(row0 + hf) * ENS + i] : PADV;
    la[hf][i] = xla_logsigmoid(x);
  }
  __syncthreads();

  int role = (w + blockIdx.x) % 3;
  if (role == 0) {
    // ---------- S: the ONE exact backward chain ----------
    float s = NEGC;
    #pragma unroll 1
    for (int ph = 0; ph <= 32; ++ph) {
      if (ph <= 31) {
        int gq = 31 - ph;
        if (gq <= 30) ckpt[((size_t)gq * BB + row) * 32 + g] = s;  // S[(gq+1)*32]
        float areg[32];
        #pragma unroll
        for (int t = 0; t < 32; ++t) areg[t] = la[half][gq * 32 + t];
        float* rg = &ring[ph & 1][half][0][0];
        #pragma unroll
        for (int t = 31; t >= 0; --t) {
          float a = areg[t];
          float prev = shup1(s);
          float sh = (g == 0) ? 0.0f : prev;      // S[i+1][g]
          float tv = a + sh;                      // a + s1
          float amax = fmaxf(s, tv);
          float snew = amax + xla_log1pf(xla_expf(-fabsf(s - tv)));  // S[i][g+1]
          rg[t * 32 + g] = tv - snew;             // d (exact sub, r10 op order)
          s = snew;
        }
      }
      __syncthreads();
    }
  } else if (role == 1) {
    // ---------- PV: exp + compare + bit-pack ----------
    #pragma unroll 1
    for (int ph = 0; ph <= 32; ++ph) {
      if (ph >= 1) {
        int gq = 32 - ph;
        int t_ = lane & 31, hf_ = lane >> 5;
        lu[hf_][t_] = jax_uniform01((uint32_t)((gq * 32 + t_) * BB + row0 + hf_));
        const float* rg = &ring[(ph - 1) & 1][half][0][0];
        uint32_t cw = 0u;
        #pragma unroll
        for (int t = 0; t < 32; ++t) {
          float d = rg[t * 32 + g];
          float u = lu[half][t];
          float p = xla_expf(d);   // clip(p,0,1) no-op for u<p with u in [0,1)
          cw |= (u < p) ? (1u << t) : 0u;
        }
        cmask[(size_t)row * NN + gq * 32 + g] = cw;
      }
      __syncthreads();
    }
  } else {
    // ---------- F: fast forward scan ----------
    float F = NEGC;
    #pragma unroll 1
    for (int ph = 0; ph <= 32; ++ph) {
      if (ph <= 31) {
        int gq = ph;
        float areg[32];
        #pragma unroll
        for (int t = 0; t < 32; ++t) areg[t] = la[half][gq * 32 + t];
        #pragma unroll
        for (int t = 0; t < 32; ++t) {
          float prev = shup1(F);
          float Fj = (g == 0) ? 0.0f : prev;
          F = fast_lae(F, areg[t] + Fj);
        }
        if (gq <= 30) fckpt[((size_t)gq * BB + row) * 32 + g] = F;  // F[(gq+1)*32]
      }
      __syncthreads();
    }
    if (g == 31) logZ[row] = F;   // F[N][32]
  }
}

// ===================== kernel 2: serial sampler (verbatim r10, passing) ============
__global__ __launch_bounds__(64) void k_samp(const uint32_t* __restrict__ cmask,
                                             uint32_t* __restrict__ bits) {
  int row = blockIdx.x;
  int lane = threadIdx.x;
  const uint32_t* base = cmask + (size_t)row * NN;
  int r = KK;
  #pragma unroll 1
  for (int q = 0; q < 16; ++q) {
    uint32_t mw = base[q * 64 + lane];   // one coalesced 256B load per 64 items
    uint32_t w0 = 0u, w1 = 0u;
    #pragma unroll
    for (int t = 0; t < 32; ++t) {
      int rl = (r > 0) ? (r - 1) : 0;
      uint32_t wv = (uint32_t)__builtin_amdgcn_readlane((int)mw, rl);
      int inc = (int)((wv >> t) & 1u) & (int)(r > 0);
      r -= inc;
      w0 |= ((uint32_t)inc) << t;
    }
    #pragma unroll
    for (int t = 0; t < 32; ++t) {
      int rl = (r > 0) ? (r - 1) : 0;
      uint32_t wv = (uint32_t)__builtin_amdgcn_readlane((int)mw, 32 + rl);
      int inc = (int)((wv >> t) & 1u) & (int)(r > 0);
      r -= inc;
      w1 |= ((uint32_t)inc) << t;
    }
    if (lane == 0) {
      bits[row * 32 + q * 2] = w0;
      bits[row * 32 + q * 2 + 1] = w1;
    }
  }
}

// ===================== kernel 3: marginals on 32-item segments =====================
__global__ __launch_bounds__(64) void k_marg(const float* __restrict__ scores,
                                             const float* __restrict__ ckpt,
                                             const float* __restrict__ fckpt,
                                             const float* __restrict__ logZ,
                                             float* __restrict__ margOut) {
  __shared__ float Ss[2][33][32];   // 8448 B
  __shared__ float laS[2][32];
  int lane = threadIdx.x;
  int g = lane & 31, half = lane >> 5;
  int rp = blockIdx.x >> 5, seg = blockIdx.x & 31;
  int row = rp * 2 + half, base = seg * 32;
  const float* srow = scores + (size_t)row * ENS;

  {
    int i0 = base + g;
    laS[half][g] = alo_fast((i0 < ENS) ? srow[i0] : PADV);
  }
  float s = (seg == 31) ? NEGC : ckpt[((size_t)seg * BB + row) * 32 + g];
  Ss[half][32][g] = s;
  #pragma unroll
  for (int t = 31; t >= 0; --t) {
    float a = laS[half][t];
    float prev = shup1(s);
    float sh = (g == 0) ? 0.0f : prev;
    s = fast_lae(s, a + sh);
    Ss[half][t][g] = s;
  }
  // single wave: DS ops in-order, no barrier needed
  float F = (seg == 0) ? NEGC : fckpt[((size_t)(seg - 1) * BB + row) * 32 + g];
  float lz = logZ[row];
  #pragma unroll 4
  for (int t = 0; t < 32; ++t) {
    int i = base + t;
    float a = laS[half][t];
    float prev = shup1(F);
    float Fj = (g == 0) ? 0.0f : prev;
    float sv = (g == 31) ? 0.0f : Ss[half][t + 1][30 - g];   // S[i+1][31-g]
    float term = fexp2((Fj + sv - lz) * L2E);                // <= ~1, no max pass
    float tot = sum_half_last(term);
    if (g == 31 && i < ENS)
      margOut[(size_t)row * ENS + i] = fexp2(a * L2E) * tot;
    F = fast_lae(F, a + Fj);
  }
}

// ===================== kernel 4: straight-through combine ==========================
__global__ __launch_bounds__(256) void k_final(const float* __restrict__ margOut,
                                               const uint32_t* __restrict__ bits,
                                               float* __restrict__ out) {
  int idx = blockIdx.x * 256 + threadIdx.x;
  if (idx >= BB * ENS) return;
  int row = idx / ENS;
  int i = idx - row * ENS;
  float marg = margOut[idx];
  uint32_t wbits = bits[row * 32 + (i >> 5)];
  float bit = (float)((wbits >> (i & 31)) & 1u);
  out[idx] = (bit - marg) + marg;
}

extern "C" void kernel_launch(void* const* d_in, const int* in_sizes, int n_in,
                              void* d_out, int out_size, void* d_ws, size_t ws_size,
                              hipStream_t stream) {
  const float* scores = (const float*)d_in[0];
  float* outbuf = (float*)d_out;
  float* margOut = outbuf + (size_t)BB * ENS;   // marginals = out upper half

  float* ws = (float*)d_ws;
  float* ckpt = ws;                                   // 31*BB*32 floats
  float* fckpt = ckpt + (size_t)31 * BB * 32;         // 31*BB*32 floats
  float* logZ = fckpt + (size_t)31 * BB * 32;         // BB floats
  uint32_t* cmask = (uint32_t*)(logZ + BB);           // BB*NN dwords (8 MB)
  uint32_t* bits = cmask + (size_t)BB * NN;           // BB*32 dwords
  (void)in_sizes; (void)n_in; (void)out_size; (void)ws_size;

  hipLaunchKernelGGL(k_scan1, dim3(BB / 2), dim3(192), 0, stream,
                     scores, ckpt, fckpt, logZ, cmask);
  hipLaunchKernelGGL(k_samp, dim3(BB), dim3(64), 0, stream, cmask, bits);
  hipLaunchKernelGGL(k_marg, dim3((BB / 2) * 32), dim3(64), 0, stream,
                     scores, ckpt, fckpt, logZ, margOut);
  hipLaunchKernelGGL(k_final, dim3((BB * ENS + 255) / 256), dim3(256), 0, stream,
                     margOut, bits, outbuf);
}

// Round 12
// 394.209 us; speedup vs baseline: 1.7162x; 1.0113x over previous
//
#include <hip/hip_runtime.h>
#include <stdint.h>

#pragma clang fp contract(off)

#define NN 1024
#define BB 2048
#define ENS 1000
#define KK 32

#define NEGC -1.0e9f
#define PADV -1.0e10f
#define L2E 1.44269504088896341f
#define LN2 0.69314718055994531f

// ===================== XLA:CPU float32 math replicas (exact path) =====================
__device__ __forceinline__ float xla_expf(float xin) {
  float x = fminf(xin, 88.3762626647950f);
  x = fmaxf(x, -88.3762626647949f);
  float fx = floorf(__builtin_fmaf(x, 1.44269504088896341f, 0.5f));
  x = __builtin_fmaf(fx, -0.693359375f, x);
  x = __builtin_fmaf(fx, 2.12194440e-4f, x);
  float z = x * x;
  float y = 1.9875691500e-4f;
  y = __builtin_fmaf(y, x, 1.3981999507e-3f);
  y = __builtin_fmaf(y, x, 8.3334519073e-3f);
  y = __builtin_fmaf(y, x, 4.1665795894e-2f);
  y = __builtin_fmaf(y, x, 1.6666665459e-1f);
  y = __builtin_fmaf(y, x, 5.0000001201e-1f);
  y = __builtin_fmaf(y, z, x);
  y = y + 1.0f;
  int n = (int)fx;
  float two_n = __int_as_float((n + 127) << 23);
  return y * two_n;
}

// exp variant for inputs provably <= 0: fminf(x, 88.37) is bit-identity there.
__device__ __forceinline__ float xla_expf_neg(float xin) {
  float x = fmaxf(xin, -88.3762626647949f);
  float fx = floorf(__builtin_fmaf(x, 1.44269504088896341f, 0.5f));
  x = __builtin_fmaf(fx, -0.693359375f, x);
  x = __builtin_fmaf(fx, 2.12194440e-4f, x);
  float z = x * x;
  float y = 1.9875691500e-4f;
  y = __builtin_fmaf(y, x, 1.3981999507e-3f);
  y = __builtin_fmaf(y, x, 8.3334519073e-3f);
  y = __builtin_fmaf(y, x, 4.1665795894e-2f);
  y = __builtin_fmaf(y, x, 1.6666665459e-1f);
  y = __builtin_fmaf(y, x, 5.0000001201e-1f);
  y = __builtin_fmaf(y, z, x);
  y = y + 1.0f;
  int n = (int)fx;
  float two_n = __int_as_float((n + 127) << 23);
  return y * two_n;
}

__device__ __forceinline__ float xla_logf(float uin) {
  int ib = __float_as_int(uin);
  float e = (float)((ib >> 23) - 126);
  float m = __int_as_float((ib & 0x007FFFFF) | 0x3F000000);
  bool lt = m < 0.707106781186547524f;
  float tmp = lt ? m : 0.0f;
  e = lt ? (e - 1.0f) : e;
  float x = m - 1.0f;
  x = x + tmp;
  float z = x * x;
  float y = 7.0376836292e-2f;
  y = __builtin_fmaf(y, x, -1.1514610310e-1f);
  y = __builtin_fmaf(y, x, 1.1676998740e-1f);
  y = __builtin_fmaf(y, x, -1.2420140846e-1f);
  y = __builtin_fmaf(y, x, 1.4249322787e-1f);
  y = __builtin_fmaf(y, x, -1.6668057665e-1f);
  y = __builtin_fmaf(y, x, 2.0000714765e-1f);
  y = __builtin_fmaf(y, x, -2.4999993993e-1f);
  y = __builtin_fmaf(y, x, 3.3333331174e-1f);
  y = y * x;
  y = y * z;
  y = __builtin_fmaf(e, -2.12194440e-4f, y);
  y = __builtin_fmaf(z, -0.5f, y);
  x = x + y;
  x = __builtin_fmaf(e, 0.693359375f, x);
  return x;
}

__device__ __forceinline__ float xla_log1pf(float x) {
  float lg = xla_logf(x + 1.0f);
  float sm = __builtin_fmaf(-0.5f, x, 1.0f) * x;
  return (fabsf(x) < 1e-4f) ? sm : lg;
}

__device__ __forceinline__ float xla_logsigmoid(float v) {
  float y = -v;
  float amax = fmaxf(y, 0.0f);
  float sp = amax + xla_log1pf(xla_expf_neg(-fabsf(y)));
  return -sp + 1e-7f;
}

// ===================== fast math (marginal path only; 2e-2 tolerance) ==============
__device__ __forceinline__ float fexp2(float x) { return __builtin_amdgcn_exp2f(x); }
__device__ __forceinline__ float flog2(float x) { return __builtin_amdgcn_logf(x); }

__device__ __forceinline__ float fast_lae(float a, float b) {
  float m = fmaxf(a, b);
  float d = -fabsf(a - b);
  float e = fexp2(d * L2E);
  return m + flog2(1.0f + e) * LN2;
}

// ===================== DPP / lane helpers =====================
template <int CTRL, int ROWM>
__device__ __forceinline__ float dppz(float x) {
  return __int_as_float(__builtin_amdgcn_update_dpp(0, __float_as_int(x), CTRL, ROWM, 0xF, false));
}

__device__ __forceinline__ float shup1(float x) { return dppz<0x138, 0xF>(x); }  // wave_shr:1

// per-half (32-lane) sum; total lands at g==31 of each half
__device__ __forceinline__ float sum_half_last(float x) {
  x += dppz<0x111, 0xF>(x);   // row_shr:1
  x += dppz<0x112, 0xF>(x);   // row_shr:2
  x += dppz<0x114, 0xF>(x);   // row_shr:4
  x += dppz<0x118, 0xF>(x);   // row_shr:8
  x += dppz<0x142, 0xA>(x);   // row_bcast15 into rows 1&3
  return x;
}

// ===================== JAX threefry2x32, key(42) =====================
__device__ __forceinline__ uint32_t rotl_(uint32_t v, int s) { return (v << s) | (v >> (32 - s)); }

__device__ __forceinline__ uint32_t threefry_fold(uint32_t x0, uint32_t x1) {
  const uint32_t ks0 = 0u;
  const uint32_t ks1 = 42u;
  const uint32_t ks2 = 0x1BD11BDAu ^ 42u;
  uint32_t v0 = x0 + ks0;
  uint32_t v1 = x1 + ks1;
#define TF_R(rr) { v0 += v1; v1 = rotl_(v1, rr); v1 ^= v0; }
  TF_R(13) TF_R(15) TF_R(26) TF_R(6)
  v0 += ks1; v1 += ks2 + 1u;
  TF_R(17) TF_R(29) TF_R(16) TF_R(24)
  v0 += ks2; v1 += ks0 + 2u;
  TF_R(13) TF_R(15) TF_R(26) TF_R(6)
  v0 += ks0; v1 += ks1 + 3u;
  TF_R(17) TF_R(29) TF_R(16) TF_R(24)
  v0 += ks1; v1 += ks2 + 4u;
  TF_R(13) TF_R(15) TF_R(26) TF_R(6)
  v0 += ks2; v1 += ks0 + 5u;
#undef TF_R
  return v0 ^ v1;
}

__device__ __forceinline__ float jax_uniform01(uint32_t m) {
  uint32_t bits = threefry_fold(0u, m);
  return __uint_as_float((bits >> 9) | 0x3F800000u) - 1.0f;
}

// ===================== THE mega kernel: everything for 4 rows per block ============
// 4 waves: phase2: w0,w1 = exact backward S+PV (one row-pair each, barrier-free,
// cmask/ckpt in LDS); w2,w3 = fast forward F (fckpt, logZ in LDS).
// phase3: w0,w1 run the serial top-k samplers (readlane chains) then join the
// marginal jobs; marginals use register-sv + DPP reduce, write into luM (dead lu).
// phase4: combined straight-through + marginal store. No workspace at all.
__global__ __launch_bounds__(256) void k_mega(const float* __restrict__ scores,
                                              float* __restrict__ out,
                                              float* __restrict__ margOut) {
  __shared__ float la[4][NN];              // 16 KiB  exact logsigmoid(a)
  __shared__ float luM[4][NN];             // 16 KiB  u values; reused as marg values
  __shared__ uint32_t cmaskL[4][32][32];   // 16 KiB  [row][group][channel] bit t
  __shared__ float ckptL[4][15][32];       // 7.5 KiB S[(k+1)*64]
  __shared__ float fckptL[4][15][32];      // 7.5 KiB F[(k+1)*64]
  __shared__ uint32_t bitsL[4][32];        // 512 B
  __shared__ float logZL[4];
  int tid = threadIdx.x, w = tid >> 6, lane = tid & 63;
  int g = lane & 31, half = lane >> 5;
  int row0 = blockIdx.x * 4;

  // ---- phase 1: stage exact logsigmoid + threefry uniforms ----
  #pragma unroll 1
  for (int n = tid; n < 4 * NN; n += 256) {
    int r = n >> 10, i = n & (NN - 1);
    float x = (i < ENS) ? scores[(size_t)(row0 + r) * ENS + i] : PADV;
    la[r][i] = xla_logsigmoid(x);
    luM[r][i] = jax_uniform01((uint32_t)(i * BB + row0 + r));
  }
  __syncthreads();

  // ---- phase 2: scans ----
  if (w < 2) {
    // exact backward S-chain + PV bit generation; pair w, row = lane half
    int lr = w * 2 + half;
    float s = NEGC;
    #pragma unroll 1
    for (int gq = 31; gq >= 0; --gq) {
      if ((gq & 1) && gq < 31) ckptL[lr][gq >> 1][g] = s;   // S[(k+1)*64], k=gq>>1
      uint32_t cw = 0u;
      #pragma unroll
      for (int t = 31; t >= 0; --t) {
        int i = gq * 32 + t;
        float a = la[lr][i];
        float u = luM[lr][i];
        float prev = shup1(s);
        float sh = (g == 0) ? 0.0f : prev;      // S[i+1][g]
        float tv = a + sh;                      // a + s1
        float amax = fmaxf(s, tv);
        float snew = amax + xla_log1pf(xla_expf_neg(-fabsf(s - tv)));  // S[i][g+1]
        float d = tv - snew;
        s = snew;
        float p = xla_expf(d);                  // p for channel g+1 (clip no-op)
        cw |= (u < p) ? (1u << t) : 0u;
      }
      cmaskL[lr][gq][g] = cw;
    }
  } else {
    // fast forward F-scan; pair w-2
    int lr = (w - 2) * 2 + half;
    float F = NEGC;
    #pragma unroll 1
    for (int gq = 0; gq <= 31; ++gq) {
      #pragma unroll
      for (int t = 0; t < 32; ++t) {
        float prev = shup1(F);
        float Fj = (g == 0) ? 0.0f : prev;
        F = fast_lae(F, la[lr][gq * 32 + t] + Fj);
      }
      if ((gq & 1) && gq < 31) fckptL[lr][gq >> 1][g] = F;  // F[(k+1)*64]
    }
    if (g == 31) logZL[lr] = F;   // F[N][32]
  }
  __syncthreads();

  // ---- phase 3a: serial top-k samplers (w0: rows 0,1; w1: rows 2,3) ----
  if (w < 2) {
    #pragma unroll 1
    for (int rh = 0; rh < 2; ++rh) {
      int lr = w * 2 + rh;
      int r = KK;
      #pragma unroll 1
      for (int q = 0; q < 16; ++q) {
        uint32_t mw = cmaskL[lr][2 * q + (lane >> 5)][lane & 31];
        uint32_t w0c = 0u, w1c = 0u;
        #pragma unroll
        for (int t = 0; t < 32; ++t) {
          int rl = (r > 0) ? (r - 1) : 0;
          uint32_t wv = (uint32_t)__builtin_amdgcn_readlane((int)mw, rl);
          int inc = (int)((wv >> t) & 1u) & (int)(r > 0);
          r -= inc;
          w0c |= ((uint32_t)inc) << t;
        }
        #pragma unroll
        for (int t = 0; t < 32; ++t) {
          int rl = (r > 0) ? (r - 1) : 0;
          uint32_t wv = (uint32_t)__builtin_amdgcn_readlane((int)mw, 32 + rl);
          int inc = (int)((wv >> t) & 1u) & (int)(r > 0);
          r -= inc;
          w1c |= ((uint32_t)inc) << t;
        }
        if (lane == 0) { bitsL[lr][2 * q] = w0c; bitsL[lr][2 * q + 1] = w1c; }
      }
    }
  }

  // ---- phase 3b: marginal jobs (32 jobs = 2 pairs x 16 segments of 64) ----
  {
    int jbeg = (w == 0) ? 9 : (w == 1) ? 25 : (w == 2) ? 0 : 16;
    int jend = (w == 0) ? 16 : (w == 1) ? 32 : (w == 2) ? 9 : 25;
    #pragma unroll 1
    for (int j = jbeg; j < jend; ++j) {
      int p = j >> 4, seg = j & 15;
      int lr = p * 2 + half;
      int base = seg * 64;
      float lz = logZL[lr];
      float s = (seg == 15) ? NEGC : ckptL[lr][seg][g];
      float sv[64];
      #pragma unroll
      for (int t = 63; t >= 0; --t) {
        float prev = shup1(s);
        float sh = (g == 0) ? 0.0f : prev;       // S[i+1][g]
        sv[t] = __shfl_xor(sh, 31, 64);          // lane g <- S[i+1][31-g]
        s = fast_lae(s, la[lr][base + t] + sh);
      }
      float F = (seg == 0) ? NEGC : fckptL[lr][seg - 1][g];
      #pragma unroll
      for (int t = 0; t < 64; ++t) {
        float a = la[lr][base + t];
        float prev = shup1(F);
        float Fj = (g == 0) ? 0.0f : prev;
        float term = fexp2((Fj + sv[t] - lz) * L2E);   // <= ~1, no max pass
        float tot = sum_half_last(term);
        if (g == 31 && (base + t) < ENS)
          luM[lr][base + t] = fexp2(a * L2E) * tot;    // marg into dead lu
        F = fast_lae(F, a + Fj);
      }
    }
  }
  __syncthreads();

  // ---- phase 4: straight-through combine + store both outputs ----
  #pragma unroll 1
  for (int n = tid; n < 4 * NN; n += 256) {
    int r = n >> 10, i = n & (NN - 1);
    if (i < ENS) {
      float m = luM[r][i];
      float bit = (float)((bitsL[r][i >> 5] >> (i & 31)) & 1u);
      size_t gi = (size_t)(row0 + r) * ENS + i;
      out[gi] = (bit - m) + m;
      margOut[gi] = m;
    }
  }
}

extern "C" void kernel_launch(void* const* d_in, const int* in_sizes, int n_in,
                              void* d_out, int out_size, void* d_ws, size_t ws_size,
                              hipStream_t stream) {
  const float* scores = (const float*)d_in[0];
  float* outbuf = (float*)d_out;
  float* margOut = outbuf + (size_t)BB * ENS;   // marginals = out upper half
  (void)in_sizes; (void)n_in; (void)out_size; (void)d_ws; (void)ws_size;

  hipLaunchKernelGGL(k_mega, dim3(BB / 4), dim3(256), 0, stream,
                     scores, outbuf, margOut);
}

// Round 13
// 346.114 us; speedup vs baseline: 1.9547x; 1.1390x over previous
//
#include <hip/hip_runtime.h>
#include <stdint.h>

#pragma clang fp contract(off)

#define NN 1024
#define BB 2048
#define ENS 1000
#define KK 32

#define NEGC -1.0e9f
#define PADV -1.0e10f
#define L2E 1.44269504088896341f
#define LN2 0.69314718055994531f

// ===================== XLA:CPU float32 math replicas (exact path) =====================
// exp variant for inputs provably <= 0: fminf(x, 88.37) is bit-identity there.
__device__ __forceinline__ float xla_expf_neg(float xin) {
  float x = fmaxf(xin, -88.3762626647949f);
  float fx = floorf(__builtin_fmaf(x, 1.44269504088896341f, 0.5f));
  x = __builtin_fmaf(fx, -0.693359375f, x);
  x = __builtin_fmaf(fx, 2.12194440e-4f, x);
  float z = x * x;
  float y = 1.9875691500e-4f;
  y = __builtin_fmaf(y, x, 1.3981999507e-3f);
  y = __builtin_fmaf(y, x, 8.3334519073e-3f);
  y = __builtin_fmaf(y, x, 4.1665795894e-2f);
  y = __builtin_fmaf(y, x, 1.6666665459e-1f);
  y = __builtin_fmaf(y, x, 5.0000001201e-1f);
  y = __builtin_fmaf(y, z, x);
  y = y + 1.0f;
  int n = (int)fx;
  float two_n = __int_as_float((n + 127) << 23);
  return y * two_n;
}

__device__ __forceinline__ float xla_logf(float uin) {
  int ib = __float_as_int(uin);
  float e = (float)((ib >> 23) - 126);
  float m = __int_as_float((ib & 0x007FFFFF) | 0x3F000000);
  bool lt = m < 0.707106781186547524f;
  float tmp = lt ? m : 0.0f;
  e = lt ? (e - 1.0f) : e;
  float x = m - 1.0f;
  x = x + tmp;
  float z = x * x;
  float y = 7.0376836292e-2f;
  y = __builtin_fmaf(y, x, -1.1514610310e-1f);
  y = __builtin_fmaf(y, x, 1.1676998740e-1f);
  y = __builtin_fmaf(y, x, -1.2420140846e-1f);
  y = __builtin_fmaf(y, x, 1.4249322787e-1f);
  y = __builtin_fmaf(y, x, -1.6668057665e-1f);
  y = __builtin_fmaf(y, x, 2.0000714765e-1f);
  y = __builtin_fmaf(y, x, -2.4999993993e-1f);
  y = __builtin_fmaf(y, x, 3.3333331174e-1f);
  y = y * x;
  y = y * z;
  y = __builtin_fmaf(e, -2.12194440e-4f, y);
  y = __builtin_fmaf(z, -0.5f, y);
  x = x + y;
  x = __builtin_fmaf(e, 0.693359375f, x);
  return x;
}

__device__ __forceinline__ float xla_log1pf(float x) {
  float lg = xla_logf(x + 1.0f);
  float sm = __builtin_fmaf(-0.5f, x, 1.0f) * x;
  return (fabsf(x) < 1e-4f) ? sm : lg;
}

__device__ __forceinline__ float xla_logsigmoid(float v) {
  float y = -v;
  float amax = fmaxf(y, 0.0f);
  float sp = amax + xla_log1pf(xla_expf_neg(-fabsf(y)));
  return -sp + 1e-7f;
}

// ===================== fast math (marginal path only; 2e-2 tolerance) ==============
__device__ __forceinline__ float fexp2(float x) { return __builtin_amdgcn_exp2f(x); }
__device__ __forceinline__ float flog2(float x) { return __builtin_amdgcn_logf(x); }

__device__ __forceinline__ float fast_lae(float a, float b) {
  float m = fmaxf(a, b);
  float d = -fabsf(a - b);
  float e = fexp2(d * L2E);
  return m + flog2(1.0f + e) * LN2;
}

// ===================== DPP / lane helpers =====================
template <int CTRL, int ROWM>
__device__ __forceinline__ float dppz(float x) {
  return __int_as_float(__builtin_amdgcn_update_dpp(0, __float_as_int(x), CTRL, ROWM, 0xF, false));
}

__device__ __forceinline__ float shup1(float x) { return dppz<0x138, 0xF>(x); }  // wave_shr:1

// per-half (32-lane) sum; total lands at g==31 of each half
__device__ __forceinline__ float sum_half_last(float x) {
  x += dppz<0x111, 0xF>(x);   // row_shr:1
  x += dppz<0x112, 0xF>(x);   // row_shr:2
  x += dppz<0x114, 0xF>(x);   // row_shr:4
  x += dppz<0x118, 0xF>(x);   // row_shr:8
  x += dppz<0x142, 0xA>(x);   // row_bcast15 into rows 1&3
  return x;
}

// ===================== JAX threefry2x32, key(42) =====================
__device__ __forceinline__ uint32_t rotl_(uint32_t v, int s) { return (v << s) | (v >> (32 - s)); }

__device__ __forceinline__ uint32_t threefry_fold(uint32_t x0, uint32_t x1) {
  const uint32_t ks0 = 0u;
  const uint32_t ks1 = 42u;
  const uint32_t ks2 = 0x1BD11BDAu ^ 42u;
  uint32_t v0 = x0 + ks0;
  uint32_t v1 = x1 + ks1;
#define TF_R(rr) { v0 += v1; v1 = rotl_(v1, rr); v1 ^= v0; }
  TF_R(13) TF_R(15) TF_R(26) TF_R(6)
  v0 += ks1; v1 += ks2 + 1u;
  TF_R(17) TF_R(29) TF_R(16) TF_R(24)
  v0 += ks2; v1 += ks0 + 2u;
  TF_R(13) TF_R(15) TF_R(26) TF_R(6)
  v0 += ks0; v1 += ks1 + 3u;
  TF_R(17) TF_R(29) TF_R(16) TF_R(24)
  v0 += ks1; v1 += ks2 + 4u;
  TF_R(13) TF_R(15) TF_R(26) TF_R(6)
  v0 += ks2; v1 += ks0 + 5u;
#undef TF_R
  return v0 ^ v1;
}

__device__ __forceinline__ float jax_uniform01(uint32_t m) {
  uint32_t bits = threefry_fold(0u, m);
  return __uint_as_float((bits >> 9) | 0x3F800000u) - 1.0f;
}

// ===================== THE mega kernel with chase scheduling =======================
// 4 rows/block, 4 waves, roles rotated by blockIdx:
//  roles 0,1 (S+PV, pair=role): ph 0..15 exact backward chain seg 15-ph (ckpt ->
//    LDS, per-channel bits -> cmaskL); ph 16,17 serial samplers (row ph-16).
//  roles 2,3 (F+marg, pair=role-2): ph 0,1 full fast F-scan (fckpt, logZ);
//    ph 2..17 marginal job for seg 17-ph (descending chase, one phase behind S).
__global__ __launch_bounds__(256) void k_mega(const float* __restrict__ scores,
                                              float* __restrict__ out,
                                              float* __restrict__ margOut) {
  __shared__ float la[4][NN];              // 16 KiB  exact logsigmoid(a)
  __shared__ float luM[4][NN];             // 16 KiB  u values; reused as marg values
  __shared__ uint32_t cmaskL[4][32][32];   // 16 KiB  [row][group][channel] bit t
  __shared__ float ckptL[4][15][32];       // 7.5 KiB S[(k+1)*64]
  __shared__ float fckptL[4][15][32];      // 7.5 KiB F[(k+1)*64]
  __shared__ uint32_t bitsL[4][32];        // 512 B
  __shared__ float logZL[4];
  int tid = threadIdx.x, w = tid >> 6, lane = tid & 63;
  int g = lane & 31, half = lane >> 5;
  int row0 = blockIdx.x * 4;
  int rol = (w + blockIdx.x) & 3;

  // ---- stage: exact logsigmoid + threefry uniforms ----
  #pragma unroll 1
  for (int n = tid; n < 4 * NN; n += 256) {
    int r = n >> 10, i = n & (NN - 1);
    float x = (i < ENS) ? scores[(size_t)(row0 + r) * ENS + i] : PADV;
    la[r][i] = xla_logsigmoid(x);
    luM[r][i] = jax_uniform01((uint32_t)(i * BB + row0 + r));
  }
  __syncthreads();

  int p = (rol < 2) ? rol : (rol - 2);
  int lr = p * 2 + half;
  float s = NEGC;    // S state
  float Fv = NEGC;   // F state

  #pragma unroll 1
  for (int ph = 0; ph < 18; ++ph) {
    if (rol < 2) {
      if (ph <= 15) {
        // ---- exact backward S-chain + PV bits, segment 15-ph ----
        int seg = 15 - ph;
        if (seg <= 14) ckptL[lr][seg][g] = s;   // S[(seg+1)*64]
        const float4* ap = (const float4*)&la[lr][seg * 64];
        const float4* up = (const float4*)&luM[lr][seg * 64];
        float4 av[16], uv[16];
        #pragma unroll
        for (int q = 0; q < 16; ++q) { av[q] = ap[q]; uv[q] = up[q]; }
        uint32_t cw0 = 0u, cw1 = 0u;
        #pragma unroll
        for (int t = 63; t >= 0; --t) {
          float a = ((const float*)&av[t >> 2])[t & 3];
          float u = ((const float*)&uv[t >> 2])[t & 3];
          float prev = shup1(s);
          float sh = (g == 0) ? 0.0f : prev;      // S[i+1][g]
          float tv = a + sh;                      // a + s1
          float amax = fmaxf(s, tv);
          float snew = amax + xla_log1pf(xla_expf_neg(-fabsf(s - tv)));  // S[i][g+1]
          float d = tv - snew;                    // <= 0 always
          s = snew;
          float pr = xla_expf_neg(d);             // p for channel g+1 (clip no-op)
          uint32_t b = (u < pr) ? 1u : 0u;
          if (t >= 32) cw1 |= b << (t - 32); else cw0 |= b << t;
        }
        cmaskL[lr][seg * 2][g] = cw0;
        cmaskL[lr][seg * 2 + 1][g] = cw1;
      } else {
        // ---- serial top-k sampler for row p*2 + (ph-16) ----
        int lrr = p * 2 + (ph - 16);
        int r = KK;
        #pragma unroll 1
        for (int q = 0; q < 16; ++q) {
          uint32_t mw = cmaskL[lrr][2 * q + (lane >> 5)][lane & 31];
          uint32_t w0c = 0u, w1c = 0u;
          #pragma unroll
          for (int t = 0; t < 32; ++t) {
            int rl = (r > 0) ? (r - 1) : 0;
            uint32_t wv = (uint32_t)__builtin_amdgcn_readlane((int)mw, rl);
            int inc = (int)((wv >> t) & 1u) & (int)(r > 0);
            r -= inc;
            w0c |= ((uint32_t)inc) << t;
          }
          #pragma unroll
          for (int t = 0; t < 32; ++t) {
            int rl = (r > 0) ? (r - 1) : 0;
            uint32_t wv = (uint32_t)__builtin_amdgcn_readlane((int)mw, 32 + rl);
            int inc = (int)((wv >> t) & 1u) & (int)(r > 0);
            r -= inc;
            w1c |= ((uint32_t)inc) << t;
          }
          if (lane == 0) { bitsL[lrr][2 * q] = w0c; bitsL[lrr][2 * q + 1] = w1c; }
        }
      }
    } else {
      if (ph <= 1) {
        // ---- fast forward F-scan, half the row per phase ----
        #pragma unroll 1
        for (int k = ph * 8; k < ph * 8 + 8; ++k) {
          #pragma unroll
          for (int t = 0; t < 64; ++t) {
            float prev = shup1(Fv);
            float Fj = (g == 0) ? 0.0f : prev;
            Fv = fast_lae(Fv, la[lr][k * 64 + t] + Fj);
          }
          if (k <= 14) fckptL[lr][k][g] = Fv;   // F[(k+1)*64]
        }
        if (ph == 1 && g == 31) logZL[lr] = Fv;  // F[N][32]
      } else {
        // ---- marginal job, segment 17-ph (chases the S chain) ----
        int seg = 17 - ph;
        int base = seg * 64;
        float lz = logZL[lr];
        float sM = (seg == 15) ? NEGC : ckptL[lr][seg][g];
        float sv[64];
        #pragma unroll
        for (int t = 63; t >= 0; --t) {
          float prev = shup1(sM);
          float sh = (g == 0) ? 0.0f : prev;       // S[i+1][g]
          sv[t] = __shfl_xor(sh, 31, 64);          // lane g <- S[i+1][31-g]
          sM = fast_lae(sM, la[lr][base + t] + sh);
        }
        float Fm = (seg == 0) ? NEGC : fckptL[lr][seg - 1][g];
        #pragma unroll
        for (int t = 0; t < 64; ++t) {
          float a = la[lr][base + t];
          float prev = shup1(Fm);
          float Fj = (g == 0) ? 0.0f : prev;
          float term = fexp2((Fj + sv[t] - lz) * L2E);   // <= ~1, no max pass
          float tot = sum_half_last(term);
          if (g == 31 && (base + t) < ENS)
            luM[lr][base + t] = fexp2(a * L2E) * tot;    // marg into dead lu slot
          Fm = fast_lae(Fm, a + Fj);
        }
      }
    }
    __syncthreads();
  }

  // ---- straight-through combine + store both outputs ----
  #pragma unroll 1
  for (int n = tid; n < 4 * NN; n += 256) {
    int r = n >> 10, i = n & (NN - 1);
    if (i < ENS) {
      float m = luM[r][i];
      float bit = (float)((bitsL[r][i >> 5] >> (i & 31)) & 1u);
      size_t gi = (size_t)(row0 + r) * ENS + i;
      out[gi] = (bit - m) + m;
      margOut[gi] = m;
    }
  }
}

extern "C" void kernel_launch(void* const* d_in, const int* in_sizes, int n_in,
                              void* d_out, int out_size, void* d_ws, size_t ws_size,
                              hipStream_t stream) {
  const float* scores = (const float*)d_in[0];
  float* outbuf = (float*)d_out;
  float* margOut = outbuf + (size_t)BB * ENS;   // marginals = out upper half
  (void)in_sizes; (void)n_in; (void)out_size; (void)d_ws; (void)ws_size;

  hipLaunchKernelGGL(k_mega, dim3(BB / 4), dim3(256), 0, stream,
                     scores, outbuf, margOut);
}